// Round 7
// baseline (422.989 us; speedup 1.0000x reference)
//
#include <hip/hip_runtime.h>

#define KK 27
#define INC 32
#define PC 64

typedef __attribute__((ext_vector_type(8))) short v8s;
typedef __attribute__((ext_vector_type(4))) float f32x4;

static __device__ __forceinline__ float b2f(ushort u) {
  union { float f; unsigned int i; } x; x.i = ((unsigned int)u) << 16; return x.f;
}
static __device__ __forceinline__ ushort f2b(float f) {
  union { float f; unsigned int i; } x; x.f = f;
  unsigned int u = x.i;
  unsigned int r = (u + 0x7FFFu + ((u >> 16) & 1u)) >> 16;
  return (ushort)r;
}

// ---------------- Kernel 1: x = relu(xf@Wt+bt) [bf16], v = relu(x@Wv+bv) [bf16]
__global__ __launch_bounds__(256) void k_prep(
    const float* __restrict__ xf, const float* __restrict__ Wt, const float* __restrict__ bt,
    const float* __restrict__ Wv, const float* __restrict__ bv,
    ushort* __restrict__ x, ushort* __restrict__ v, int N)
{
  int tid = threadIdx.x, lane = tid & 63, w = tid >> 6;
  int vbase = blockIdx.x * 16;
  __shared__ float xin[16][32];
  __shared__ float xs[16][64];
  if (tid < 128) {
    int r = tid >> 3, c4 = tid & 7;
    int n = vbase + r;
    float4 d = make_float4(0.f, 0.f, 0.f, 0.f);
    if (n < N) d = *(const float4*)(xf + (size_t)n * INC + c4 * 4);
    *(float4*)(&xin[r][c4 * 4]) = d;
  }
  __syncthreads();
  float a0 = bt[lane], a1 = a0, a2 = a0, a3 = a0;
  #pragma unroll
  for (int i = 0; i < INC; ++i) {
    float wt = Wt[i * PC + lane];
    a0 += xin[w * 4 + 0][i] * wt; a1 += xin[w * 4 + 1][i] * wt;
    a2 += xin[w * 4 + 2][i] * wt; a3 += xin[w * 4 + 3][i] * wt;
  }
  a0 = fmaxf(a0, 0.f); a1 = fmaxf(a1, 0.f); a2 = fmaxf(a2, 0.f); a3 = fmaxf(a3, 0.f);
  xs[w * 4 + 0][lane] = a0; xs[w * 4 + 1][lane] = a1;
  xs[w * 4 + 2][lane] = a2; xs[w * 4 + 3][lane] = a3;
  {
    int n0 = vbase + w * 4;
    if (n0 + 0 < N) x[(size_t)(n0 + 0) * PC + lane] = f2b(a0);
    if (n0 + 1 < N) x[(size_t)(n0 + 1) * PC + lane] = f2b(a1);
    if (n0 + 2 < N) x[(size_t)(n0 + 2) * PC + lane] = f2b(a2);
    if (n0 + 3 < N) x[(size_t)(n0 + 3) * PC + lane] = f2b(a3);
  }
  float v0 = bv[lane], v1 = v0, v2 = v0, v3 = v0;
  #pragma unroll
  for (int i = 0; i < PC; ++i) {
    float wv = Wv[i * PC + lane];
    v0 += xs[w * 4 + 0][i] * wv; v1 += xs[w * 4 + 1][i] * wv;
    v2 += xs[w * 4 + 2][i] * wv; v3 += xs[w * 4 + 3][i] * wv;
  }
  {
    int n0 = vbase + w * 4;
    if (n0 + 0 < N) v[(size_t)(n0 + 0) * PC + lane] = f2b(fmaxf(v0, 0.f));
    if (n0 + 1 < N) v[(size_t)(n0 + 1) * PC + lane] = f2b(fmaxf(v1, 0.f));
    if (n0 + 2 < N) v[(size_t)(n0 + 2) * PC + lane] = f2b(fmaxf(v2, 0.f));
    if (n0 + 3 < N) v[(size_t)(n0 + 3) * PC + lane] = f2b(fmaxf(v3, 0.f));
  }
}

// ---------------- Kernel 2: q + softmax attn. 16 voxels/block, 16 lanes/voxel.
// Branchless mask + depth-2 rolling prefetch of x-row and neighbor coords.
__global__ __launch_bounds__(256) void k_attn(
    const ushort* __restrict__ x, const int* __restrict__ nbr_idx, const int* __restrict__ nbr_mask,
    const int* __restrict__ coords,
    const float* __restrict__ Wpos, const float* __restrict__ bpos,
    const float* __restrict__ Wq, const float* __restrict__ bq,
    const float* __restrict__ proj, float* __restrict__ attn, int N)
{
  int tid = threadIdx.x;
  int g = tid >> 4, l = tid & 15;
  int nb = blockIdx.x * 16;
  int n = nb + g;
  __shared__ int jm[16][KK];
  __shared__ int cds[16][3];
  for (int i = tid; i < 16 * KK; i += 256) {
    int r = i / KK, k = i % KK;
    int nn = nb + r;
    int val = -1;
    if (nn < N && nbr_mask[(size_t)nn * KK + k]) val = nbr_idx[(size_t)nn * KK + k];
    jm[r][k] = val;
  }
  if (tid < 48) {
    int r = tid / 3, c = tid % 3;
    int nn = nb + r;
    cds[r][c] = (nn < N) ? coords[nn * 3 + c] : 0;
  }
  __syncthreads();
  if (n >= N) return;
  int ch = l * 4;
  float4 wp0 = *(const float4*)(Wpos + 0 * PC + ch);
  float4 wp1 = *(const float4*)(Wpos + 1 * PC + ch);
  float4 wp2 = *(const float4*)(Wpos + 2 * PC + ch);
  float4 bp  = *(const float4*)(bpos + ch);
  int cx = cds[g][0], cy = cds[g][1], cz = cds[g][2];
  float q0 = 0.f, q1 = 0.f, q2 = 0.f, q3 = 0.f;

  // rolling prefetch slots a (k) and b (k+1)
  int ja = jm[g][0], jb = jm[g][1];
  ushort4 xva, xvb; int cxa, cya, cza, cxb, cyb, czb;
  {
    int jj = max(ja, 0);
    xva = *(const ushort4*)(x + (size_t)jj * PC + ch);
    cxa = coords[jj * 3 + 0]; cya = coords[jj * 3 + 1]; cza = coords[jj * 3 + 2];
  }
  {
    int jj = max(jb, 0);
    xvb = *(const ushort4*)(x + (size_t)jj * PC + ch);
    cxb = coords[jj * 3 + 0]; cyb = coords[jj * 3 + 1]; czb = coords[jj * 3 + 2];
  }

  for (int k = 0; k < KK; ++k) {
    // grab current (slot a)
    int jc = ja;
    ushort4 xv = xva;
    int jx = cxa, jy = cya, jz = cza;
    // rotate b -> a
    ja = jb; xva = xvb; cxa = cxb; cya = cyb; cza = czb;
    // issue k+2 into slot b (always; row 0 if absent)
    int jn = (k + 2 < KK) ? jm[g][k + 2] : -1;
    jb = jn;
    {
      int jj = max(jn, 0);
      xvb = *(const ushort4*)(x + (size_t)jj * PC + ch);
      cxb = coords[jj * 3 + 0]; cyb = coords[jj * 3 + 1]; czb = coords[jj * 3 + 2];
    }
    // compute with current
    float msk = (jc >= 0) ? 1.f : 0.f;
    float rx = (float)(jx - cx);
    float ry = (float)(jy - cy);
    float rz = (float)(jz - cz);
    float4 wq = *(const float4*)(Wq + k * PC + ch);
    float p0 = fmaxf(rx * wp0.x + ry * wp1.x + rz * wp2.x + bp.x, 0.f);
    float p1 = fmaxf(rx * wp0.y + ry * wp1.y + rz * wp2.y + bp.y, 0.f);
    float p2 = fmaxf(rx * wp0.z + ry * wp1.z + rz * wp2.z + bp.z, 0.f);
    float p3 = fmaxf(rx * wp0.w + ry * wp1.w + rz * wp2.w + bp.w, 0.f);
    q0 += msk * (b2f(xv.x) + p0) * wq.x;
    q1 += msk * (b2f(xv.y) + p1) * wq.y;
    q2 += msk * (b2f(xv.z) + p2) * wq.z;
    q3 += msk * (b2f(xv.w) + p3) * wq.w;
  }
  float qs = q0 + q1 + q2 + q3;
  #pragma unroll
  for (int off = 1; off < 16; off <<= 1) qs += __shfl_xor(qs, off);
  if (l == 0) {
    float q = fmaxf(qs + bq[0], 0.f);
    float lg[4], mx = -1e30f;
    #pragma unroll
    for (int m = 0; m < 4; ++m) { lg[m] = q * proj[m] * 0.1f; mx = fmaxf(mx, lg[m]); }
    float s = 0.f;
    #pragma unroll
    for (int m = 0; m < 4; ++m) { lg[m] = __expf(lg[m] - mx); s += lg[m]; }
    float inv = 1.f / s;
    #pragma unroll
    for (int m = 0; m < 4; ++m) attn[(size_t)n * 4 + m] = lg[m] * inv;
  }
}

// ---------------- Kernel 3: repack W_code f32 [m,k,c,d] -> bf16 Bp[s][kg][col][j]
__global__ __launch_bounds__(256) void k_prepB(const float* __restrict__ Wcode, ushort* __restrict__ Bp)
{
  int i = blockIdx.x * 256 + threadIdx.x;   // 54*4*256*8 = 442368
  int j = i & 7;
  int col = (i >> 3) & 255;
  int kg = (i >> 11) & 3;
  int s = i >> 13;
  int k = s * 32 + kg * 8 + j;
  int m = col >> 6, d = col & 63;
  int knbr = k >> 6, c = k & 63;
  Bp[i] = f2b(Wcode[(((m * KK + knbr) * 64) + c) * 64 + d]);
}

// ---------------- Kernel 4: gathered GEMM [64x1728]x[1728x256], 4x4 wave tiles,
// R6 GEMM loop (B before gathers, depth-1 prefetch, 1 barrier/kn) +
// R5 2-pass epilogue (LDS 26.6 KB for occupancy)
__global__ __launch_bounds__(256) void k_code(
    const ushort* __restrict__ v, const int* __restrict__ nbr_idx, const int* __restrict__ nbr_mask,
    const ushort* __restrict__ Bp, const float* __restrict__ attn,
    const float* __restrict__ xf, const float* __restrict__ Wd, const float* __restrict__ bd,
    const float* __restrict__ bcode, float* __restrict__ out, int N)
{
  const int tid = threadIdx.x;
  const int lane = tid & 63, w = tid >> 6;
  const int base = blockIdx.x * 64;

  __shared__ __align__(16) union SM {
    struct { ushort As[2][4096]; int jm[64][KK]; } g;         // GEMM phase (23.3 KB)
    struct { ushort pbuf[4][32][72]; float xfs[64][32]; } e;  // epilogue (26.6 KB)
  } sm;

  // stage combined neighbor indices (idx if mask else -1), coalesced
  for (int i = tid; i < 64 * KK; i += 256) {
    int r = i / KK, k = i % KK;
    int n = base + r;
    int val = -1;
    if (n < N && nbr_mask[(size_t)n * KK + k]) val = nbr_idx[(size_t)n * KK + k];
    sm.g.jm[r][k] = val;
  }

  const int r0 = tid >> 3, cc0 = tid & 7;
  const int r1 = r0 + 32,  cc1 = cc0;
  const int sc0 = cc0 ^ (r0 & 7), sc1 = cc1 ^ (r1 & 7);

  __syncthreads();  // jm ready

  // prologue: stage neighbor 0 into As[0]
  {
    int j0 = sm.g.jm[r0][0], j1 = sm.g.jm[r1][0];
    uint4 p0 = make_uint4(0u, 0u, 0u, 0u), p1 = make_uint4(0u, 0u, 0u, 0u);
    if (j0 >= 0) p0 = *(const uint4*)(v + (size_t)j0 * PC + cc0 * 8);
    if (j1 >= 0) p1 = *(const uint4*)(v + (size_t)j1 * PC + cc1 * 8);
    *(uint4*)(&sm.g.As[0][r0 * 64 + sc0 * 8]) = p0;
    *(uint4*)(&sm.g.As[0][r1 * 64 + sc1 * 8]) = p1;
  }
  __syncthreads();

  f32x4 acc[4][4] = {};
  const ushort* bbase = Bp + (size_t)(lane >> 4) * 2048 + (size_t)((w << 6) + (lane & 15)) * 8;

  for (int kn = 0; kn < KK; ++kn) {
    const int cur = kn & 1, nxt = cur ^ 1;
    // (1) B fragments — issued FIRST (short-latency L2; MFMA vmcnt stops here)
    v8s bf0[4], bf1[4];
    {
      const ushort* bb0 = bbase + (size_t)(8 * kn) * 2048;
      const ushort* bb1 = bb0 + 4 * 2048;
      #pragma unroll
      for (int nt = 0; nt < 4; ++nt) {
        bf0[nt] = *(const v8s*)(bb0 + nt * 128);
        bf1[nt] = *(const v8s*)(bb1 + nt * 128);
      }
    }
    // (2) next neighbor's gathers (long latency, drain under MFMA)
    uint4 pre0 = make_uint4(0u, 0u, 0u, 0u), pre1 = make_uint4(0u, 0u, 0u, 0u);
    if (kn + 1 < KK) {
      int j0 = sm.g.jm[r0][kn + 1], j1 = sm.g.jm[r1][kn + 1];
      if (j0 >= 0) pre0 = *(const uint4*)(v + (size_t)j0 * PC + cc0 * 8);
      if (j1 >= 0) pre1 = *(const uint4*)(v + (size_t)j1 * PC + cc1 * 8);
    }
    // (3) A fragments + MFMA
    #pragma unroll
    for (int s2 = 0; s2 < 2; ++s2) {
      v8s af[4];
      const int cc = s2 * 4 + (lane >> 4);
      #pragma unroll
      for (int mt = 0; mt < 4; ++mt) {
        const int r = mt * 16 + (lane & 15);
        const int sc = cc ^ (r & 7);
        af[mt] = *(const v8s*)(&sm.g.As[cur][r * 64 + sc * 8]);
      }
      #pragma unroll
      for (int mt = 0; mt < 4; ++mt)
        #pragma unroll
        for (int nt = 0; nt < 4; ++nt)
          acc[mt][nt] = __builtin_amdgcn_mfma_f32_16x16x32_bf16(
              af[mt], (s2 ? bf1[nt] : bf0[nt]), acc[mt][nt], 0, 0, 0);
    }
    // (4) commit gather(kn+1) to As[nxt]
    if (kn + 1 < KK) {
      *(uint4*)(&sm.g.As[nxt][r0 * 64 + sc0 * 8]) = pre0;
      *(uint4*)(&sm.g.As[nxt][r1 * 64 + sc1 * 8]) = pre1;
    }
    __syncthreads();
  }

  // ---- epilogue: 2 row-passes; publish att*relu(code+bc) bf16 partials, then sum
  const int ln = lane & 15, grp = lane >> 4;
  float bcv[4];
  #pragma unroll
  for (int nt = 0; nt < 4; ++nt) bcv[nt] = bcode[w * PC + nt * 16 + ln];
  const float bdv = bd[lane];

  // stage xf rows once (coalesced); consumed after the publish barrier
  for (int i2 = tid; i2 < 2048; i2 += 256) {
    int r = i2 >> 5, c = i2 & 31;
    int n = base + r;
    sm.e.xfs[r][c] = (n < N) ? xf[(size_t)n * INC + c] : 0.f;
  }

  #pragma unroll
  for (int pass = 0; pass < 2; ++pass) {
    if (pass) __syncthreads();   // pbuf of pass 0 fully consumed
    #pragma unroll
    for (int mh = 0; mh < 2; ++mh) {
      const int mt = pass * 2 + mh;
      #pragma unroll
      for (int i = 0; i < 4; ++i) {
        int row = mt * 16 + grp * 4 + i;
        int n = base + row;
        float a = (n < N) ? attn[(size_t)n * 4 + w] : 0.f;
        #pragma unroll
        for (int nt = 0; nt < 4; ++nt) {
          float p = a * fmaxf(acc[mt][nt][i] + bcv[nt], 0.f);
          sm.e.pbuf[w][row - pass * 32][nt * 16 + ln] = f2b(p);
        }
      }
    }
    __syncthreads();
    // consume: wave w sums rows pass*32 + w*8 .. +7, d = lane
    float racc[8];
    #pragma unroll
    for (int lr = 0; lr < 8; ++lr) racc[lr] = bdv;
    for (int c = 0; c < INC; ++c) {
      float wd = Wd[c * PC + lane];
      #pragma unroll
      for (int lr = 0; lr < 8; ++lr)
        racc[lr] += sm.e.xfs[pass * 32 + w * 8 + lr][c] * wd;
    }
    #pragma unroll
    for (int lr = 0; lr < 8; ++lr) {
      int row = pass * 32 + w * 8 + lr;
      int n = base + row;
      if (n < N) {
        float val = racc[lr];
        #pragma unroll
        for (int mm = 0; mm < 4; ++mm) val += b2f(sm.e.pbuf[mm][row - pass * 32][lane]);
        out[(size_t)n * PC + lane] = fmaxf(val, 0.f);
      }
    }
  }
}

extern "C" void kernel_launch(void* const* d_in, const int* in_sizes, int n_in,
                              void* d_out, int out_size, void* d_ws, size_t ws_size,
                              hipStream_t stream)
{
  const float* xf     = (const float*)d_in[0];
  const int* nbr_idx  = (const int*)d_in[1];
  const int* nbr_mask = (const int*)d_in[2];
  const int* coords   = (const int*)d_in[3];
  const float* Wt     = (const float*)d_in[4];
  const float* bt     = (const float*)d_in[5];
  const float* Wd     = (const float*)d_in[6];
  const float* bd     = (const float*)d_in[7];
  const float* Wpos   = (const float*)d_in[8];
  const float* bpos   = (const float*)d_in[9];
  const float* Wq     = (const float*)d_in[10];
  const float* bq     = (const float*)d_in[11];
  const float* proj   = (const float*)d_in[12];
  const float* Wv     = (const float*)d_in[13];
  const float* bv     = (const float*)d_in[14];
  const float* Wcode  = (const float*)d_in[15];
  const float* bcode  = (const float*)d_in[16];
  float* out = (float*)d_out;

  int N = in_sizes[0] / INC;

  char* ws = (char*)d_ws;
  size_t off = 0;
  auto alloc = [&](size_t bytes) {
    off = (off + 255) & ~(size_t)255;
    void* p = ws + off;
    off += bytes;
    return p;
  };
  ushort* x_ws = (ushort*)alloc((size_t)N * PC * 2);
  ushort* v_ws = (ushort*)alloc((size_t)N * PC * 2);
  float*  a_ws = (float*)alloc((size_t)N * 4 * 4);
  ushort* B_ws = (ushort*)alloc((size_t)54 * 4 * 256 * 8 * 2);
  (void)ws_size;

  hipLaunchKernelGGL(k_prep, dim3((N + 15) / 16), dim3(256), 0, stream,
                     xf, Wt, bt, Wv, bv, x_ws, v_ws, N);
  hipLaunchKernelGGL(k_attn, dim3((N + 15) / 16), dim3(256), 0, stream,
                     x_ws, nbr_idx, nbr_mask, coords, Wpos, bpos, Wq, bq, proj, a_ws, N);
  hipLaunchKernelGGL(k_prepB, dim3((54 * 4 * 256 * 8) / 256), dim3(256), 0, stream,
                     Wcode, B_ws);
  hipLaunchKernelGGL(k_code, dim3((N + 63) / 64), dim3(256), 0, stream,
                     v_ws, nbr_idx, nbr_mask, B_ws, a_ws, xf, Wd, bd, bcode, out, N);
}

// Round 8
// 291.408 us; speedup vs baseline: 1.4515x; 1.4515x over previous
//
#include <hip/hip_runtime.h>

#define KK 27
#define INC 32
#define PC 64

typedef __attribute__((ext_vector_type(8))) short v8s;
typedef __attribute__((ext_vector_type(4))) float f32x4;

static __device__ __forceinline__ float b2f(ushort u) {
  union { float f; unsigned int i; } x; x.i = ((unsigned int)u) << 16; return x.f;
}
static __device__ __forceinline__ ushort f2b(float f) {
  union { float f; unsigned int i; } x; x.f = f;
  unsigned int u = x.i;
  unsigned int r = (u + 0x7FFFu + ((u >> 16) & 1u)) >> 16;
  return (ushort)r;
}

// ---------------- Kernel 1: x = relu(xf@Wt+bt) [bf16], v = relu(x@Wv+bv) [bf16]
__global__ __launch_bounds__(256) void k_prep(
    const float* __restrict__ xf, const float* __restrict__ Wt, const float* __restrict__ bt,
    const float* __restrict__ Wv, const float* __restrict__ bv,
    ushort* __restrict__ x, ushort* __restrict__ v, int N)
{
  int tid = threadIdx.x, lane = tid & 63, w = tid >> 6;
  int vbase = blockIdx.x * 16;
  __shared__ float xin[16][32];
  __shared__ float xs[16][64];
  if (tid < 128) {
    int r = tid >> 3, c4 = tid & 7;
    int n = vbase + r;
    float4 d = make_float4(0.f, 0.f, 0.f, 0.f);
    if (n < N) d = *(const float4*)(xf + (size_t)n * INC + c4 * 4);
    *(float4*)(&xin[r][c4 * 4]) = d;
  }
  __syncthreads();
  float a0 = bt[lane], a1 = a0, a2 = a0, a3 = a0;
  #pragma unroll
  for (int i = 0; i < INC; ++i) {
    float wt = Wt[i * PC + lane];
    a0 += xin[w * 4 + 0][i] * wt; a1 += xin[w * 4 + 1][i] * wt;
    a2 += xin[w * 4 + 2][i] * wt; a3 += xin[w * 4 + 3][i] * wt;
  }
  a0 = fmaxf(a0, 0.f); a1 = fmaxf(a1, 0.f); a2 = fmaxf(a2, 0.f); a3 = fmaxf(a3, 0.f);
  xs[w * 4 + 0][lane] = a0; xs[w * 4 + 1][lane] = a1;
  xs[w * 4 + 2][lane] = a2; xs[w * 4 + 3][lane] = a3;
  {
    int n0 = vbase + w * 4;
    if (n0 + 0 < N) x[(size_t)(n0 + 0) * PC + lane] = f2b(a0);
    if (n0 + 1 < N) x[(size_t)(n0 + 1) * PC + lane] = f2b(a1);
    if (n0 + 2 < N) x[(size_t)(n0 + 2) * PC + lane] = f2b(a2);
    if (n0 + 3 < N) x[(size_t)(n0 + 3) * PC + lane] = f2b(a3);
  }
  float v0 = bv[lane], v1 = v0, v2 = v0, v3 = v0;
  #pragma unroll
  for (int i = 0; i < PC; ++i) {
    float wv = Wv[i * PC + lane];
    v0 += xs[w * 4 + 0][i] * wv; v1 += xs[w * 4 + 1][i] * wv;
    v2 += xs[w * 4 + 2][i] * wv; v3 += xs[w * 4 + 3][i] * wv;
  }
  {
    int n0 = vbase + w * 4;
    if (n0 + 0 < N) v[(size_t)(n0 + 0) * PC + lane] = f2b(fmaxf(v0, 0.f));
    if (n0 + 1 < N) v[(size_t)(n0 + 1) * PC + lane] = f2b(fmaxf(v1, 0.f));
    if (n0 + 2 < N) v[(size_t)(n0 + 2) * PC + lane] = f2b(fmaxf(v2, 0.f));
    if (n0 + 3 < N) v[(size_t)(n0 + 3) * PC + lane] = f2b(fmaxf(v3, 0.f));
  }
}

// ---------------- Kernel 2: q + softmax attn. 16 voxels/block, 16 lanes/voxel.
// Branchless mask + depth-2 rolling prefetch of x-row and neighbor coords.
__global__ __launch_bounds__(256) void k_attn(
    const ushort* __restrict__ x, const int* __restrict__ nbr_idx, const int* __restrict__ nbr_mask,
    const int* __restrict__ coords,
    const float* __restrict__ Wpos, const float* __restrict__ bpos,
    const float* __restrict__ Wq, const float* __restrict__ bq,
    const float* __restrict__ proj, float* __restrict__ attn, int N)
{
  int tid = threadIdx.x;
  int g = tid >> 4, l = tid & 15;
  int nb = blockIdx.x * 16;
  int n = nb + g;
  __shared__ int jm[16][KK];
  __shared__ int cds[16][3];
  for (int i = tid; i < 16 * KK; i += 256) {
    int r = i / KK, k = i % KK;
    int nn = nb + r;
    int val = -1;
    if (nn < N && nbr_mask[(size_t)nn * KK + k]) val = nbr_idx[(size_t)nn * KK + k];
    jm[r][k] = val;
  }
  if (tid < 48) {
    int r = tid / 3, c = tid % 3;
    int nn = nb + r;
    cds[r][c] = (nn < N) ? coords[nn * 3 + c] : 0;
  }
  __syncthreads();
  if (n >= N) return;
  int ch = l * 4;
  float4 wp0 = *(const float4*)(Wpos + 0 * PC + ch);
  float4 wp1 = *(const float4*)(Wpos + 1 * PC + ch);
  float4 wp2 = *(const float4*)(Wpos + 2 * PC + ch);
  float4 bp  = *(const float4*)(bpos + ch);
  int cx = cds[g][0], cy = cds[g][1], cz = cds[g][2];
  float q0 = 0.f, q1 = 0.f, q2 = 0.f, q3 = 0.f;

  // rolling prefetch slots a (k) and b (k+1)
  int ja = jm[g][0], jb = jm[g][1];
  ushort4 xva, xvb; int cxa, cya, cza, cxb, cyb, czb;
  {
    int jj = max(ja, 0);
    xva = *(const ushort4*)(x + (size_t)jj * PC + ch);
    cxa = coords[jj * 3 + 0]; cya = coords[jj * 3 + 1]; cza = coords[jj * 3 + 2];
  }
  {
    int jj = max(jb, 0);
    xvb = *(const ushort4*)(x + (size_t)jj * PC + ch);
    cxb = coords[jj * 3 + 0]; cyb = coords[jj * 3 + 1]; czb = coords[jj * 3 + 2];
  }

  for (int k = 0; k < KK; ++k) {
    int jc = ja;
    ushort4 xv = xva;
    int jx = cxa, jy = cya, jz = cza;
    ja = jb; xva = xvb; cxa = cxb; cya = cyb; cza = czb;
    int jn = (k + 2 < KK) ? jm[g][k + 2] : -1;
    jb = jn;
    {
      int jj = max(jn, 0);
      xvb = *(const ushort4*)(x + (size_t)jj * PC + ch);
      cxb = coords[jj * 3 + 0]; cyb = coords[jj * 3 + 1]; czb = coords[jj * 3 + 2];
    }
    float msk = (jc >= 0) ? 1.f : 0.f;
    float rx = (float)(jx - cx);
    float ry = (float)(jy - cy);
    float rz = (float)(jz - cz);
    float4 wq = *(const float4*)(Wq + k * PC + ch);
    float p0 = fmaxf(rx * wp0.x + ry * wp1.x + rz * wp2.x + bp.x, 0.f);
    float p1 = fmaxf(rx * wp0.y + ry * wp1.y + rz * wp2.y + bp.y, 0.f);
    float p2 = fmaxf(rx * wp0.z + ry * wp1.z + rz * wp2.z + bp.z, 0.f);
    float p3 = fmaxf(rx * wp0.w + ry * wp1.w + rz * wp2.w + bp.w, 0.f);
    q0 += msk * (b2f(xv.x) + p0) * wq.x;
    q1 += msk * (b2f(xv.y) + p1) * wq.y;
    q2 += msk * (b2f(xv.z) + p2) * wq.z;
    q3 += msk * (b2f(xv.w) + p3) * wq.w;
  }
  float qs = q0 + q1 + q2 + q3;
  #pragma unroll
  for (int off = 1; off < 16; off <<= 1) qs += __shfl_xor(qs, off);
  if (l == 0) {
    float q = fmaxf(qs + bq[0], 0.f);
    float lg[4], mx = -1e30f;
    #pragma unroll
    for (int m = 0; m < 4; ++m) { lg[m] = q * proj[m] * 0.1f; mx = fmaxf(mx, lg[m]); }
    float s = 0.f;
    #pragma unroll
    for (int m = 0; m < 4; ++m) { lg[m] = __expf(lg[m] - mx); s += lg[m]; }
    float inv = 1.f / s;
    #pragma unroll
    for (int m = 0; m < 4; ++m) attn[(size_t)n * 4 + m] = lg[m] * inv;
  }
}

// ---------------- Kernel 3: repack W_code f32 [m,k,c,d] -> bf16 Bp[s][kg][col][j]
__global__ __launch_bounds__(256) void k_prepB(const float* __restrict__ Wcode, ushort* __restrict__ Bp)
{
  int i = blockIdx.x * 256 + threadIdx.x;   // 54*4*256*8 = 442368
  int j = i & 7;
  int col = (i >> 3) & 255;
  int kg = (i >> 11) & 3;
  int s = i >> 13;
  int k = s * 32 + kg * 8 + j;
  int m = col >> 6, d = col & 63;
  int knbr = k >> 6, c = k & 63;
  Bp[i] = f2b(Wcode[(((m * KK + knbr) * 64) + c) * 64 + d]);
}

// ---------------- Kernel 4: gathered GEMM [64x1728]x[1728x256], 4x4 wave tiles,
// 3-buffer LDS ring with EARLY COMMIT: commit gather(kn+1) (loaded a full
// iteration ago) before MFMA; issue gather(kn+2); MFMA waits only on B
// (in-order vmcnt); the fresh gather stays outstanding across the barrier.
// One-pass R6 epilogue (proven 76-VGPR shape).
__global__ __launch_bounds__(256) void k_code(
    const ushort* __restrict__ v, const int* __restrict__ nbr_idx, const int* __restrict__ nbr_mask,
    const ushort* __restrict__ Bp, const float* __restrict__ attn,
    const float* __restrict__ xf, const float* __restrict__ Wd, const float* __restrict__ bd,
    const float* __restrict__ bcode, float* __restrict__ out, int N)
{
  const int tid = threadIdx.x;
  const int lane = tid & 63, w = tid >> 6;
  const int base = blockIdx.x * 64;

  __shared__ __align__(16) union SM {
    struct { ushort As[3][4096]; int jm[64][KK]; } g;     // GEMM phase (30.9 KB)
    ushort pbuf[4][64][68];                               // epilogue phase (34 KB)
  } sm;

  // stage combined neighbor indices (idx if mask else -1), coalesced
  for (int i = tid; i < 64 * KK; i += 256) {
    int r = i / KK, k = i % KK;
    int n = base + r;
    int val = -1;
    if (n < N && nbr_mask[(size_t)n * KK + k]) val = nbr_idx[(size_t)n * KK + k];
    sm.g.jm[r][k] = val;
  }

  const int r0 = tid >> 3, cc0 = tid & 7;
  const int r1 = r0 + 32,  cc1 = cc0;
  const int sc0 = cc0 ^ (r0 & 7), sc1 = cc1 ^ (r1 & 7);

  __syncthreads();  // jm ready

  // prologue: gather(0) -> As[0]; gather(1) -> regs R
  uint4 R0 = make_uint4(0u,0u,0u,0u), R1 = R0;
  {
    int j0 = sm.g.jm[r0][0], j1 = sm.g.jm[r1][0];
    uint4 p0 = make_uint4(0u, 0u, 0u, 0u), p1 = p0;
    if (j0 >= 0) p0 = *(const uint4*)(v + (size_t)j0 * PC + cc0 * 8);
    if (j1 >= 0) p1 = *(const uint4*)(v + (size_t)j1 * PC + cc1 * 8);
    int jc = sm.g.jm[r0][1], jd = sm.g.jm[r1][1];
    if (jc >= 0) R0 = *(const uint4*)(v + (size_t)jc * PC + cc0 * 8);
    if (jd >= 0) R1 = *(const uint4*)(v + (size_t)jd * PC + cc1 * 8);
    *(uint4*)(&sm.g.As[0][r0 * 64 + sc0 * 8]) = p0;
    *(uint4*)(&sm.g.As[0][r1 * 64 + sc1 * 8]) = p1;
  }
  __syncthreads();

  f32x4 acc[4][4] = {};
  const ushort* bbase = Bp + (size_t)(lane >> 4) * 2048 + (size_t)((w << 6) + (lane & 15)) * 8;

  int cur = 0, nx = 1;
  for (int kn = 0; kn < KK; ++kn) {
    // (1) B fragments — issued FIRST (short-latency; MFMA's vmcnt stops here)
    v8s bf0[4], bf1[4];
    {
      const ushort* bb0 = bbase + (size_t)(8 * kn) * 2048;
      const ushort* bb1 = bb0 + 4 * 2048;
      #pragma unroll
      for (int nt = 0; nt < 4; ++nt) {
        bf0[nt] = *(const v8s*)(bb0 + nt * 128);
        bf1[nt] = *(const v8s*)(bb1 + nt * 128);
      }
    }
    // (2) EARLY COMMIT: gather(kn+1), in flight since last iteration -> As[nx]
    if (kn + 1 < KK) {
      *(uint4*)(&sm.g.As[nx][r0 * 64 + sc0 * 8]) = R0;
      *(uint4*)(&sm.g.As[nx][r1 * 64 + sc1 * 8]) = R1;
    }
    // (3) issue gather(kn+2) -> R; stays outstanding across the barrier
    R0 = make_uint4(0u,0u,0u,0u); R1 = R0;
    if (kn + 2 < KK) {
      int j0 = sm.g.jm[r0][kn + 2], j1 = sm.g.jm[r1][kn + 2];
      if (j0 >= 0) R0 = *(const uint4*)(v + (size_t)j0 * PC + cc0 * 8);
      if (j1 >= 0) R1 = *(const uint4*)(v + (size_t)j1 * PC + cc1 * 8);
    }
    // (4) A fragments + MFMA on As[cur]
    #pragma unroll
    for (int s2 = 0; s2 < 2; ++s2) {
      v8s af[4];
      const int cc = s2 * 4 + (lane >> 4);
      #pragma unroll
      for (int mt = 0; mt < 4; ++mt) {
        const int r = mt * 16 + (lane & 15);
        const int sc = cc ^ (r & 7);
        af[mt] = *(const v8s*)(&sm.g.As[cur][r * 64 + sc * 8]);
      }
      #pragma unroll
      for (int mt = 0; mt < 4; ++mt)
        #pragma unroll
        for (int nt = 0; nt < 4; ++nt)
          acc[mt][nt] = __builtin_amdgcn_mfma_f32_16x16x32_bf16(
              af[mt], (s2 ? bf1[nt] : bf0[nt]), acc[mt][nt], 0, 0, 0);
    }
    __syncthreads();
    cur = nx; nx = (nx == 2) ? 0 : nx + 1;
  }

  // ---- epilogue phase 1: every wave publishes att*relu(code+bc) as bf16 partials
  const int ln = lane & 15, grp = lane >> 4;
  {
    float bcv[4];
    #pragma unroll
    for (int nt = 0; nt < 4; ++nt) bcv[nt] = bcode[w * PC + nt * 16 + ln];
    #pragma unroll
    for (int mt = 0; mt < 4; ++mt) {
      #pragma unroll
      for (int i = 0; i < 4; ++i) {
        int row = mt * 16 + grp * 4 + i;
        int n = base + row;
        float a = (n < N) ? attn[(size_t)n * 4 + w] : 0.f;
        #pragma unroll
        for (int nt = 0; nt < 4; ++nt) {
          float p = a * fmaxf(acc[mt][nt][i] + bcv[nt], 0.f);
          sm.pbuf[w][row][nt * 16 + ln] = f2b(p);
        }
      }
    }
  }
  __syncthreads();

  // ---- epilogue phase 2: wave w handles rows w*16..w*16+15; sum partials + residual
  const int rbase = (w << 4) + (grp << 2);
  float racc[4][4] = {};   // [i][q]
  for (int c = 0; c < INC; ++c) {
    float xv[4];
    #pragma unroll
    for (int i = 0; i < 4; ++i) {
      int n = base + rbase + i;
      xv[i] = (n < N) ? xf[(size_t)n * INC + c] : 0.f;
    }
    #pragma unroll
    for (int q = 0; q < 4; ++q) {
      float wd = Wd[c * PC + (q << 4) + ln];
      #pragma unroll
      for (int i = 0; i < 4; ++i) racc[i][q] += xv[i] * wd;
    }
  }
  #pragma unroll
  for (int q = 0; q < 4; ++q) {
    int d = (q << 4) + ln;
    float bdv = bd[d];
    #pragma unroll
    for (int i = 0; i < 4; ++i) {
      int row = rbase + i;
      int n = base + row;
      if (n < N) {
        float val = racc[i][q] + bdv;
        #pragma unroll
        for (int mm = 0; mm < 4; ++mm) val += b2f(sm.pbuf[mm][row][d]);
        out[(size_t)n * PC + d] = fmaxf(val, 0.f);
      }
    }
  }
}

extern "C" void kernel_launch(void* const* d_in, const int* in_sizes, int n_in,
                              void* d_out, int out_size, void* d_ws, size_t ws_size,
                              hipStream_t stream)
{
  const float* xf     = (const float*)d_in[0];
  const int* nbr_idx  = (const int*)d_in[1];
  const int* nbr_mask = (const int*)d_in[2];
  const int* coords   = (const int*)d_in[3];
  const float* Wt     = (const float*)d_in[4];
  const float* bt     = (const float*)d_in[5];
  const float* Wd     = (const float*)d_in[6];
  const float* bd     = (const float*)d_in[7];
  const float* Wpos   = (const float*)d_in[8];
  const float* bpos   = (const float*)d_in[9];
  const float* Wq     = (const float*)d_in[10];
  const float* bq     = (const float*)d_in[11];
  const float* proj   = (const float*)d_in[12];
  const float* Wv     = (const float*)d_in[13];
  const float* bv     = (const float*)d_in[14];
  const float* Wcode  = (const float*)d_in[15];
  const float* bcode  = (const float*)d_in[16];
  float* out = (float*)d_out;

  int N = in_sizes[0] / INC;

  char* ws = (char*)d_ws;
  size_t off = 0;
  auto alloc = [&](size_t bytes) {
    off = (off + 255) & ~(size_t)255;
    void* p = ws + off;
    off += bytes;
    return p;
  };
  ushort* x_ws = (ushort*)alloc((size_t)N * PC * 2);
  ushort* v_ws = (ushort*)alloc((size_t)N * PC * 2);
  float*  a_ws = (float*)alloc((size_t)N * 4 * 4);
  ushort* B_ws = (ushort*)alloc((size_t)54 * 4 * 256 * 8 * 2);
  (void)ws_size;

  hipLaunchKernelGGL(k_prep, dim3((N + 15) / 16), dim3(256), 0, stream,
                     xf, Wt, bt, Wv, bv, x_ws, v_ws, N);
  hipLaunchKernelGGL(k_attn, dim3((N + 15) / 16), dim3(256), 0, stream,
                     x_ws, nbr_idx, nbr_mask, coords, Wpos, bpos, Wq, bq, proj, a_ws, N);
  hipLaunchKernelGGL(k_prepB, dim3((54 * 4 * 256 * 8) / 256), dim3(256), 0, stream,
                     Wcode, B_ws);
  hipLaunchKernelGGL(k_code, dim3((N + 63) / 64), dim3(256), 0, stream,
                     v_ws, nbr_idx, nbr_mask, B_ws, a_ws, xf, Wd, bd, bcode, out, N);
}

// Round 9
// 275.634 us; speedup vs baseline: 1.5346x; 1.0572x over previous
//
#include <hip/hip_runtime.h>

#define KK 27
#define INC 32
#define PC 64

typedef __attribute__((ext_vector_type(8))) short v8s;
typedef __attribute__((ext_vector_type(4))) float f32x4;

static __device__ __forceinline__ float b2f(ushort u) {
  union { float f; unsigned int i; } x; x.i = ((unsigned int)u) << 16; return x.f;
}
static __device__ __forceinline__ ushort f2b(float f) {
  union { float f; unsigned int i; } x; x.f = f;
  unsigned int u = x.i;
  unsigned int r = (u + 0x7FFFu + ((u >> 16) & 1u)) >> 16;
  return (ushort)r;
}

// ---------------- Kernel 1: x = relu(xf@Wt+bt) [bf16], v = relu(x@Wv+bv) [bf16]
__global__ __launch_bounds__(256) void k_prep(
    const float* __restrict__ xf, const float* __restrict__ Wt, const float* __restrict__ bt,
    const float* __restrict__ Wv, const float* __restrict__ bv,
    ushort* __restrict__ x, ushort* __restrict__ v, int N)
{
  int tid = threadIdx.x, lane = tid & 63, w = tid >> 6;
  int vbase = blockIdx.x * 16;
  __shared__ float xin[16][32];
  __shared__ float xs[16][64];
  if (tid < 128) {
    int r = tid >> 3, c4 = tid & 7;
    int n = vbase + r;
    float4 d = make_float4(0.f, 0.f, 0.f, 0.f);
    if (n < N) d = *(const float4*)(xf + (size_t)n * INC + c4 * 4);
    *(float4*)(&xin[r][c4 * 4]) = d;
  }
  __syncthreads();
  float a0 = bt[lane], a1 = a0, a2 = a0, a3 = a0;
  #pragma unroll
  for (int i = 0; i < INC; ++i) {
    float wt = Wt[i * PC + lane];
    a0 += xin[w * 4 + 0][i] * wt; a1 += xin[w * 4 + 1][i] * wt;
    a2 += xin[w * 4 + 2][i] * wt; a3 += xin[w * 4 + 3][i] * wt;
  }
  a0 = fmaxf(a0, 0.f); a1 = fmaxf(a1, 0.f); a2 = fmaxf(a2, 0.f); a3 = fmaxf(a3, 0.f);
  xs[w * 4 + 0][lane] = a0; xs[w * 4 + 1][lane] = a1;
  xs[w * 4 + 2][lane] = a2; xs[w * 4 + 3][lane] = a3;
  {
    int n0 = vbase + w * 4;
    if (n0 + 0 < N) x[(size_t)(n0 + 0) * PC + lane] = f2b(a0);
    if (n0 + 1 < N) x[(size_t)(n0 + 1) * PC + lane] = f2b(a1);
    if (n0 + 2 < N) x[(size_t)(n0 + 2) * PC + lane] = f2b(a2);
    if (n0 + 3 < N) x[(size_t)(n0 + 3) * PC + lane] = f2b(a3);
  }
  float v0 = bv[lane], v1 = v0, v2 = v0, v3 = v0;
  #pragma unroll
  for (int i = 0; i < PC; ++i) {
    float wv = Wv[i * PC + lane];
    v0 += xs[w * 4 + 0][i] * wv; v1 += xs[w * 4 + 1][i] * wv;
    v2 += xs[w * 4 + 2][i] * wv; v3 += xs[w * 4 + 3][i] * wv;
  }
  {
    int n0 = vbase + w * 4;
    if (n0 + 0 < N) v[(size_t)(n0 + 0) * PC + lane] = f2b(fmaxf(v0, 0.f));
    if (n0 + 1 < N) v[(size_t)(n0 + 1) * PC + lane] = f2b(fmaxf(v1, 0.f));
    if (n0 + 2 < N) v[(size_t)(n0 + 2) * PC + lane] = f2b(fmaxf(v2, 0.f));
    if (n0 + 3 < N) v[(size_t)(n0 + 3) * PC + lane] = f2b(fmaxf(v3, 0.f));
  }
}

// ---------------- Kernel 2: q + softmax attn. 16 voxels/block, 16 lanes/voxel.
__global__ __launch_bounds__(256) void k_attn(
    const ushort* __restrict__ x, const int* __restrict__ nbr_idx, const int* __restrict__ nbr_mask,
    const int* __restrict__ coords,
    const float* __restrict__ Wpos, const float* __restrict__ bpos,
    const float* __restrict__ Wq, const float* __restrict__ bq,
    const float* __restrict__ proj, float* __restrict__ attn, int N)
{
  int tid = threadIdx.x;
  int g = tid >> 4, l = tid & 15;
  int nb = blockIdx.x * 16;
  int n = nb + g;
  __shared__ int jm[16][KK];
  __shared__ int cds[16][3];
  for (int i = tid; i < 16 * KK; i += 256) {
    int r = i / KK, k = i % KK;
    int nn = nb + r;
    int val = -1;
    if (nn < N && nbr_mask[(size_t)nn * KK + k]) val = nbr_idx[(size_t)nn * KK + k];
    jm[r][k] = val;
  }
  if (tid < 48) {
    int r = tid / 3, c = tid % 3;
    int nn = nb + r;
    cds[r][c] = (nn < N) ? coords[nn * 3 + c] : 0;
  }
  __syncthreads();
  if (n >= N) return;
  int ch = l * 4;
  float4 wp0 = *(const float4*)(Wpos + 0 * PC + ch);
  float4 wp1 = *(const float4*)(Wpos + 1 * PC + ch);
  float4 wp2 = *(const float4*)(Wpos + 2 * PC + ch);
  float4 bp  = *(const float4*)(bpos + ch);
  int cx = cds[g][0], cy = cds[g][1], cz = cds[g][2];
  float q0 = 0.f, q1 = 0.f, q2 = 0.f, q3 = 0.f;

  int ja = jm[g][0], jb = jm[g][1];
  ushort4 xva, xvb; int cxa, cya, cza, cxb, cyb, czb;
  {
    int jj = max(ja, 0);
    xva = *(const ushort4*)(x + (size_t)jj * PC + ch);
    cxa = coords[jj * 3 + 0]; cya = coords[jj * 3 + 1]; cza = coords[jj * 3 + 2];
  }
  {
    int jj = max(jb, 0);
    xvb = *(const ushort4*)(x + (size_t)jj * PC + ch);
    cxb = coords[jj * 3 + 0]; cyb = coords[jj * 3 + 1]; czb = coords[jj * 3 + 2];
  }

  for (int k = 0; k < KK; ++k) {
    int jc = ja;
    ushort4 xv = xva;
    int jx = cxa, jy = cya, jz = cza;
    ja = jb; xva = xvb; cxa = cxb; cya = cyb; cza = czb;
    int jn = (k + 2 < KK) ? jm[g][k + 2] : -1;
    jb = jn;
    {
      int jj = max(jn, 0);
      xvb = *(const ushort4*)(x + (size_t)jj * PC + ch);
      cxb = coords[jj * 3 + 0]; cyb = coords[jj * 3 + 1]; czb = coords[jj * 3 + 2];
    }
    float msk = (jc >= 0) ? 1.f : 0.f;
    float rx = (float)(jx - cx);
    float ry = (float)(jy - cy);
    float rz = (float)(jz - cz);
    float4 wq = *(const float4*)(Wq + k * PC + ch);
    float p0 = fmaxf(rx * wp0.x + ry * wp1.x + rz * wp2.x + bp.x, 0.f);
    float p1 = fmaxf(rx * wp0.y + ry * wp1.y + rz * wp2.y + bp.y, 0.f);
    float p2 = fmaxf(rx * wp0.z + ry * wp1.z + rz * wp2.z + bp.z, 0.f);
    float p3 = fmaxf(rx * wp0.w + ry * wp1.w + rz * wp2.w + bp.w, 0.f);
    q0 += msk * (b2f(xv.x) + p0) * wq.x;
    q1 += msk * (b2f(xv.y) + p1) * wq.y;
    q2 += msk * (b2f(xv.z) + p2) * wq.z;
    q3 += msk * (b2f(xv.w) + p3) * wq.w;
  }
  float qs = q0 + q1 + q2 + q3;
  #pragma unroll
  for (int off = 1; off < 16; off <<= 1) qs += __shfl_xor(qs, off);
  if (l == 0) {
    float q = fmaxf(qs + bq[0], 0.f);
    float lg[4], mx = -1e30f;
    #pragma unroll
    for (int m = 0; m < 4; ++m) { lg[m] = q * proj[m] * 0.1f; mx = fmaxf(mx, lg[m]); }
    float s = 0.f;
    #pragma unroll
    for (int m = 0; m < 4; ++m) { lg[m] = __expf(lg[m] - mx); s += lg[m]; }
    float inv = 1.f / s;
    #pragma unroll
    for (int m = 0; m < 4; ++m) attn[(size_t)n * 4 + m] = lg[m] * inv;
  }
}

// ---------------- Kernel 3: repack W_code f32 [m,k,c,d] -> bf16 Bp[s][kg][col][j]
__global__ __launch_bounds__(256) void k_prepB(const float* __restrict__ Wcode, ushort* __restrict__ Bp)
{
  int i = blockIdx.x * 256 + threadIdx.x;   // 54*4*256*8 = 442368
  int j = i & 7;
  int col = (i >> 3) & 255;
  int kg = (i >> 11) & 3;
  int s = i >> 13;
  int k = s * 32 + kg * 8 + j;
  int m = col >> 6, d = col & 63;
  int knbr = k >> 6, c = k & 63;
  Bp[i] = f2b(Wcode[(((m * KK + knbr) * 64) + c) * 64 + d]);
}

// ---------------- Kernel 3b: Wd f32 [k=32][d=64] -> bf16 Wdp[d][k] (B-fragment layout)
__global__ __launch_bounds__(256) void k_prepD(const float* __restrict__ Wd, ushort* __restrict__ Wdp)
{
  int i = blockIdx.x * 256 + threadIdx.x;   // 2048
  int col = i >> 5, k = i & 31;
  Wdp[i] = f2b(Wd[k * PC + col]);
}

// ---------------- Kernel 4: gathered GEMM [64x1728]x[1728x256], wave w owns
// cols {m*64 + w*16 + ln} for all m -> per-lane m-sum, NO cross-wave epilogue.
// 3-buffer LDS ring, early commit, B-before-gather. Residual via 4 MFMAs.
__global__ __launch_bounds__(256) void k_code(
    const ushort* __restrict__ v, const int* __restrict__ nbr_idx, const int* __restrict__ nbr_mask,
    const ushort* __restrict__ Bp, const float* __restrict__ attn,
    const float* __restrict__ xf, const ushort* __restrict__ Wdp, const float* __restrict__ bd,
    const float* __restrict__ bcode, float* __restrict__ out, int N)
{
  const int tid = threadIdx.x;
  const int lane = tid & 63, w = tid >> 6;
  const int base = blockIdx.x * 64;

  __shared__ __align__(16) union SM {
    struct { ushort As[3][4096]; int jm[64][KK]; } g;   // GEMM phase (31.5 KB)
    struct { ushort xfb[64][40]; } e;                   // epilogue (5.1 KB)
  } sm;

  for (int i = tid; i < 64 * KK; i += 256) {
    int r = i / KK, k = i % KK;
    int n = base + r;
    int val = -1;
    if (n < N && nbr_mask[(size_t)n * KK + k]) val = nbr_idx[(size_t)n * KK + k];
    sm.g.jm[r][k] = val;
  }

  const int r0 = tid >> 3, cc0 = tid & 7;
  const int r1 = r0 + 32,  cc1 = cc0;
  const int sc0 = cc0 ^ (r0 & 7), sc1 = cc1 ^ (r1 & 7);

  __syncthreads();  // jm ready

  // prologue: gather(0) -> As[0]; gather(1) -> regs R
  uint4 R0 = make_uint4(0u,0u,0u,0u), R1 = R0;
  {
    int j0 = sm.g.jm[r0][0], j1 = sm.g.jm[r1][0];
    uint4 p0 = make_uint4(0u, 0u, 0u, 0u), p1 = p0;
    if (j0 >= 0) p0 = *(const uint4*)(v + (size_t)j0 * PC + cc0 * 8);
    if (j1 >= 0) p1 = *(const uint4*)(v + (size_t)j1 * PC + cc1 * 8);
    int jc = sm.g.jm[r0][1], jd = sm.g.jm[r1][1];
    if (jc >= 0) R0 = *(const uint4*)(v + (size_t)jc * PC + cc0 * 8);
    if (jd >= 0) R1 = *(const uint4*)(v + (size_t)jd * PC + cc1 * 8);
    *(uint4*)(&sm.g.As[0][r0 * 64 + sc0 * 8]) = p0;
    *(uint4*)(&sm.g.As[0][r1 * 64 + sc1 * 8]) = p1;
  }
  __syncthreads();

  f32x4 acc[4][4] = {};
  // col = nt*64 + w*16 + (lane&15)  -> nt stride = 512 ushorts
  const ushort* bbase = Bp + (size_t)(lane >> 4) * 2048 + (size_t)((w << 4) + (lane & 15)) * 8;

  int cur = 0, nx = 1;
  for (int kn = 0; kn < KK; ++kn) {
    // (1) B fragments — issued FIRST (short-latency; MFMA's vmcnt stops here)
    v8s bf0[4], bf1[4];
    {
      const ushort* bb0 = bbase + (size_t)(8 * kn) * 2048;
      const ushort* bb1 = bb0 + 4 * 2048;
      #pragma unroll
      for (int nt = 0; nt < 4; ++nt) {
        bf0[nt] = *(const v8s*)(bb0 + nt * 512);
        bf1[nt] = *(const v8s*)(bb1 + nt * 512);
      }
    }
    // (2) EARLY COMMIT: gather(kn+1), in flight since last iteration -> As[nx]
    if (kn + 1 < KK) {
      *(uint4*)(&sm.g.As[nx][r0 * 64 + sc0 * 8]) = R0;
      *(uint4*)(&sm.g.As[nx][r1 * 64 + sc1 * 8]) = R1;
    }
    // (3) issue gather(kn+2) -> R; stays outstanding across the barrier
    R0 = make_uint4(0u,0u,0u,0u); R1 = R0;
    if (kn + 2 < KK) {
      int j0 = sm.g.jm[r0][kn + 2], j1 = sm.g.jm[r1][kn + 2];
      if (j0 >= 0) R0 = *(const uint4*)(v + (size_t)j0 * PC + cc0 * 8);
      if (j1 >= 0) R1 = *(const uint4*)(v + (size_t)j1 * PC + cc1 * 8);
    }
    // (4) A fragments + MFMA on As[cur]
    #pragma unroll
    for (int s2 = 0; s2 < 2; ++s2) {
      v8s af[4];
      const int cc = s2 * 4 + (lane >> 4);
      #pragma unroll
      for (int mt = 0; mt < 4; ++mt) {
        const int r = mt * 16 + (lane & 15);
        const int sc = cc ^ (r & 7);
        af[mt] = *(const v8s*)(&sm.g.As[cur][r * 64 + sc * 8]);
      }
      #pragma unroll
      for (int mt = 0; mt < 4; ++mt)
        #pragma unroll
        for (int nt = 0; nt < 4; ++nt)
          acc[mt][nt] = __builtin_amdgcn_mfma_f32_16x16x32_bf16(
              af[mt], (s2 ? bf1[nt] : bf0[nt]), acc[mt][nt], 0, 0, 0);
    }
    __syncthreads();
    cur = nx; nx = (nx == 2) ? 0 : nx + 1;
  }

  // ---- epilogue (no cross-wave traffic): per-lane m-sum + MFMA residual
  // stage xf as bf16 [64][40] (16B-aligned rows)
  for (int i2 = tid; i2 < 2048; i2 += 256) {
    int r = i2 >> 5, c = i2 & 31;
    int n = base + r;
    sm.e.xfb[r][c] = (n < N) ? f2b(xf[(size_t)n * INC + c]) : (ushort)0;
  }
  __syncthreads();

  const int ln = lane & 15, grp = lane >> 4;
  const int d = (w << 4) + ln;
  // residual = xf @ Wd via 4 MFMAs (K=32)
  v8s wdf = *(const v8s*)(Wdp + (size_t)d * 32 + grp * 8);
  f32x4 res[4];
  #pragma unroll
  for (int mt = 0; mt < 4; ++mt) {
    v8s af = *(const v8s*)(&sm.e.xfb[mt * 16 + ln][grp * 8]);
    f32x4 z = {0.f, 0.f, 0.f, 0.f};
    res[mt] = __builtin_amdgcn_mfma_f32_16x16x32_bf16(af, wdf, z, 0, 0, 0);
  }
  float bcv[4];
  #pragma unroll
  for (int nt = 0; nt < 4; ++nt) bcv[nt] = bcode[nt * PC + d];
  const float bdv = bd[d];
  #pragma unroll
  for (int mt = 0; mt < 4; ++mt) {
    #pragma unroll
    for (int i = 0; i < 4; ++i) {
      int row = mt * 16 + grp * 4 + i;
      int n = base + row;
      if (n < N) {
        float4 a4 = *(const float4*)(attn + (size_t)n * 4);
        float val = res[mt][i] + bdv;
        val += a4.x * fmaxf(acc[mt][0][i] + bcv[0], 0.f);
        val += a4.y * fmaxf(acc[mt][1][i] + bcv[1], 0.f);
        val += a4.z * fmaxf(acc[mt][2][i] + bcv[2], 0.f);
        val += a4.w * fmaxf(acc[mt][3][i] + bcv[3], 0.f);
        out[(size_t)n * PC + d] = fmaxf(val, 0.f);
      }
    }
  }
}

extern "C" void kernel_launch(void* const* d_in, const int* in_sizes, int n_in,
                              void* d_out, int out_size, void* d_ws, size_t ws_size,
                              hipStream_t stream)
{
  const float* xf     = (const float*)d_in[0];
  const int* nbr_idx  = (const int*)d_in[1];
  const int* nbr_mask = (const int*)d_in[2];
  const int* coords   = (const int*)d_in[3];
  const float* Wt     = (const float*)d_in[4];
  const float* bt     = (const float*)d_in[5];
  const float* Wd     = (const float*)d_in[6];
  const float* bd     = (const float*)d_in[7];
  const float* Wpos   = (const float*)d_in[8];
  const float* bpos   = (const float*)d_in[9];
  const float* Wq     = (const float*)d_in[10];
  const float* bq     = (const float*)d_in[11];
  const float* proj   = (const float*)d_in[12];
  const float* Wv     = (const float*)d_in[13];
  const float* bv     = (const float*)d_in[14];
  const float* Wcode  = (const float*)d_in[15];
  const float* bcode  = (const float*)d_in[16];
  float* out = (float*)d_out;

  int N = in_sizes[0] / INC;

  char* ws = (char*)d_ws;
  size_t off = 0;
  auto alloc = [&](size_t bytes) {
    off = (off + 255) & ~(size_t)255;
    void* p = ws + off;
    off += bytes;
    return p;
  };
  ushort* x_ws = (ushort*)alloc((size_t)N * PC * 2);
  ushort* v_ws = (ushort*)alloc((size_t)N * PC * 2);
  float*  a_ws = (float*)alloc((size_t)N * 4 * 4);
  ushort* B_ws = (ushort*)alloc((size_t)54 * 4 * 256 * 8 * 2);
  ushort* D_ws = (ushort*)alloc((size_t)2048 * 2);
  (void)ws_size;

  hipLaunchKernelGGL(k_prep, dim3((N + 15) / 16), dim3(256), 0, stream,
                     xf, Wt, bt, Wv, bv, x_ws, v_ws, N);
  hipLaunchKernelGGL(k_attn, dim3((N + 15) / 16), dim3(256), 0, stream,
                     x_ws, nbr_idx, nbr_mask, coords, Wpos, bpos, Wq, bq, proj, a_ws, N);
  hipLaunchKernelGGL(k_prepB, dim3((54 * 4 * 256 * 8) / 256), dim3(256), 0, stream,
                     Wcode, B_ws);
  hipLaunchKernelGGL(k_prepD, dim3(8), dim3(256), 0, stream, Wd, D_ws);
  hipLaunchKernelGGL(k_code, dim3((N + 63) / 64), dim3(256), 0, stream,
                     v_ws, nbr_idx, nbr_mask, B_ws, a_ws, xf, D_ws, bd, bcode, out, N);
}